// Round 4
// baseline (65.884 us; speedup 1.0000x reference)
//
#include <hip/hip_runtime.h>

#define NV 128   // vessels (N)
#define NBATCH 256
#define NH 128   // hidden
#define CH 32    // j-chunk
#define NCHUNK 4

// Detect whether the sequence_mask buffer is byte-backed (numpy bool) or
// word-backed (int32/float32). For word-backed, bytes at offset 4i+1 are
// always 0x00; for a ~90%-true byte bool mask they are mostly 1.
__global__ void mask_detect_kernel(const unsigned char* __restrict__ mb,
                                   int* __restrict__ flag) {
  __shared__ int s;
  if (threadIdx.x == 0) s = 0;
  __syncthreads();
  int acc = 0;
  for (int i = threadIdx.x; i < 1024; i += blockDim.x) acc += mb[4 * i + 1];
  atomicAdd(&s, acc);
  __syncthreads();
  if (threadIdx.x == 0) *flag = (s == 0) ? 1 : 0;
}

__launch_bounds__(256)
__global__ void spatial_attn_kernel(const float* __restrict__ hidden,   // (N,B,H)
                                    const float* __restrict__ dist,     // (B,N,N)
                                    const float* __restrict__ brg,      // (B,N,N)
                                    const float* __restrict__ hdg,      // (B,N,N)
                                    const unsigned char* __restrict__ maskraw,
                                    const float* __restrict__ domain,   // (24,24)
                                    const int* __restrict__ flagp,
                                    float* __restrict__ out) {          // (B,N,H)
  // Chunked LDS: w^T [j][i] and h [j][hh], both j-rows of 128 f32, XOR-swizzled.
  __shared__ __align__(16) float wlds[CH * NV];
  __shared__ __align__(16) float hlds[CH * NH];
  __shared__ float dom[24 * 24];
  __shared__ float maskf[NV];

  const int tid = threadIdx.x;
  const int b = blockIdx.x;

  for (int i = tid; i < 576; i += 256) dom[i] = domain[i];
  if (tid < NV) {
    const int kind = *flagp;
    int m = kind ? ((const int*)maskraw)[b * NV + tid]
                 : (int)maskraw[b * NV + tid];
    maskf[tid] = (m != 0) ? 1.0f : 0.0f;
  }
  __syncthreads();

  const int tx = tid & 15;   // hh-tile group
  const int ty = tid >> 4;   // i-tile group
  const int hh0 = tx * 8;
  const int i0 = ty * 8;

  float acc[8][8];
#pragma unroll
  for (int r = 0; r < 8; ++r)
#pragma unroll
    for (int c = 0; c < 8; ++c) acc[r][c] = 0.0f;

  const float* dB = dist + (size_t)b * NV * NV;
  const float* bB = brg + (size_t)b * NV * NV;
  const float* gB = hdg + (size_t)b * NV * NV;

  for (int cs = 0; cs < NCHUNK; ++cs) {
    const int jc = cs * CH;

    // ---- stage weights for j in [jc, jc+CH), all i ----
#pragma unroll
    for (int it = 0; it < 4; ++it) {
      const int v = it * 256 + tid;   // float4 index in chunk
      const int i = v >> 3;           // 8 float4 per row
      const int jl0 = (v & 7) << 2;   // local j of first element
      const int gidx = i * NV + jc + jl0;
      const float4 dd = *(const float4*)&dB[gidx];
      const float4 bb = *(const float4*)&bB[gidx];
      const float4 gg = *(const float4*)&gB[gidx];
      const float mi = maskf[i];
      const float dv[4] = {dd.x, dd.y, dd.z, dd.w};
      const float bv[4] = {bb.x, bb.y, bb.z, bb.w};
      const float gv[4] = {gg.x, gg.y, gg.z, gg.w};
#pragma unroll
      for (int q = 0; q < 4; ++q) {
        const int jl = jl0 + q;
        float w = 0.0f;
        if (mi * maskf[jc + jl] != 0.0f) {
          // Mimic XLA: divide-by-constant is rewritten to multiply by the
          // f32-rounded reciprocal. f32-div and f64-div both flip a sparse
          // set of floor buckets vs this (identical 0.413 absmax in R1/R2).
          const int i1 = min(23, max(0, (int)floorf(gv[q] * (1.0f / 15.0f))));
          const int i2 = min(23, max(0, (int)floorf(bv[q] * (1.0f / 15.0f))));
          const float t = dom[i1 * 24 + i2] - dv[q];
          w = fmaxf(t, 0.0f) + log1pf(expf(-fabsf(t)));  // stable softplus
        }
        // masked pairs: softplus(dom - 1e24) == 0.0f exactly -> w = 0
        const int sw = ((jl >> 2) & 7) << 2;
        wlds[(jl << 7) + (i ^ sw)] = w;  // transposed write, swizzled
      }
    }

    // ---- stage hidden rows j in [jc, jc+CH), natural layout ----
    {
      const int f4 = (tid & 31) << 2;  // column of float4
      const int jb = tid >> 5;         // 0..7
#pragma unroll
      for (int it = 0; it < 4; ++it) {
        const int jl = jb + it * 8;
        const int j = jc + jl;
        const float4 hv =
            *(const float4*)&hidden[(size_t)(j * NBATCH + b) * NH + f4];
        const int sw = ((jl >> 2) & 7) << 2;
        *(float4*)&hlds[(jl << 7) + (f4 ^ sw)] = hv;
      }
    }
    __syncthreads();

    // ---- matmul over this chunk: acc[i][hh] += w[i][j]*h[j][hh] ----
    int row = (tx << 2) & (CH - 1);  // per-thread j-skew spreads swizzle banks
#pragma unroll
    for (int jj = 0; jj < CH; ++jj) {
      const int sw = ((row >> 2) & 7) << 2;
      const int base = row << 7;
      const float4 w0 = *(const float4*)&wlds[base + (i0 ^ sw)];
      const float4 w1 = *(const float4*)&wlds[base + ((i0 + 4) ^ sw)];
      const float4 h0 = *(const float4*)&hlds[base + (hh0 ^ sw)];
      const float4 h1 = *(const float4*)&hlds[base + ((hh0 + 4) ^ sw)];
      const float wr[8] = {w0.x, w0.y, w0.z, w0.w, w1.x, w1.y, w1.z, w1.w};
      const float hc[8] = {h0.x, h0.y, h0.z, h0.w, h1.x, h1.y, h1.z, h1.w};
#pragma unroll
      for (int r = 0; r < 8; ++r)
#pragma unroll
        for (int c = 0; c < 8; ++c)
          acc[r][c] = fmaf(wr[r], hc[c], acc[r][c]);
      row = (row + 1) & (CH - 1);
    }
    __syncthreads();
  }

  // ---- epilogue: tanh + row mask + coalesced store ----
  float* oB = out + (size_t)b * NV * NH;
#pragma unroll
  for (int r = 0; r < 8; ++r) {
    const float mi = maskf[i0 + r];
    float4 o0, o1;
    o0.x = tanhf(acc[r][0]) * mi;
    o0.y = tanhf(acc[r][1]) * mi;
    o0.z = tanhf(acc[r][2]) * mi;
    o0.w = tanhf(acc[r][3]) * mi;
    o1.x = tanhf(acc[r][4]) * mi;
    o1.y = tanhf(acc[r][5]) * mi;
    o1.z = tanhf(acc[r][6]) * mi;
    o1.w = tanhf(acc[r][7]) * mi;
    float* op = &oB[(i0 + r) * NH + hh0];
    *(float4*)&op[0] = o0;
    *(float4*)&op[4] = o1;
  }
}

extern "C" void kernel_launch(void* const* d_in, const int* in_sizes, int n_in,
                              void* d_out, int out_size, void* d_ws, size_t ws_size,
                              hipStream_t stream) {
  const float* hidden = (const float*)d_in[0];
  const float* dist = (const float*)d_in[1];
  const float* brg = (const float*)d_in[2];
  const float* hdg = (const float*)d_in[3];
  const unsigned char* mask = (const unsigned char*)d_in[4];
  const float* domain = (const float*)d_in[5];
  float* out = (float*)d_out;
  int* flag = (int*)d_ws;

  mask_detect_kernel<<<1, 256, 0, stream>>>(mask, flag);
  spatial_attn_kernel<<<256, 256, 0, stream>>>(hidden, dist, brg, hdg, mask,
                                               domain, flag, out);
}

// Round 5
// 46.038 us; speedup vs baseline: 1.4311x; 1.4311x over previous
//
#include <hip/hip_runtime.h>

#define NV 128     // vessels (N)
#define NBATCH 256
#define NH 128     // hidden
#define CH 32      // j-chunk
#define IB 32      // i-rows per block
#define NCHUNK 4   // 128 / CH

// Detect whether the sequence_mask buffer is byte-backed (numpy bool) or
// word-backed (int32/float32): word-backed has byte1 == 0 everywhere.
__global__ void mask_detect_kernel(const unsigned char* __restrict__ mb,
                                   int* __restrict__ flag) {
  __shared__ int s;
  if (threadIdx.x == 0) s = 0;
  __syncthreads();
  int acc = 0;
  for (int i = threadIdx.x; i < 1024; i += blockDim.x) acc += mb[4 * i + 1];
  atomicAdd(&s, acc);
  __syncthreads();
  if (threadIdx.x == 0) *flag = (s == 0) ? 1 : 0;
}

__launch_bounds__(256, 4)  // cap VGPR <= 128 -> 4 waves/SIMD, 4 blocks/CU
__global__ void spatial_attn_kernel(const float* __restrict__ hidden,   // (N,B,H)
                                    const float* __restrict__ dist,     // (B,N,N)
                                    const float* __restrict__ brg,      // (B,N,N)
                                    const float* __restrict__ hdg,      // (B,N,N)
                                    const unsigned char* __restrict__ maskraw,
                                    const float* __restrict__ domain,   // (24,24)
                                    const int* __restrict__ flagp,
                                    float* __restrict__ out) {          // (B,N,H)
  __shared__ __align__(16) float wlds[CH * IB];   // [j][i_loc]  4 KB
  __shared__ __align__(16) float hlds[CH * NH];   // [j][hh]    16 KB
  __shared__ float dom[24 * 24];
  __shared__ float maskf[NV];

  const int tid = threadIdx.x;
  const int b = blockIdx.x >> 2;        // batch
  const int ibase = (blockIdx.x & 3) * IB;  // i-quarter of this batch

  for (int k = tid; k < 576; k += 256) dom[k] = domain[k];
  if (tid < NV) {
    const int kind = *flagp;
    const int m = kind ? ((const int*)maskraw)[b * NV + tid]
                       : (int)maskraw[b * NV + tid];
    maskf[tid] = (m != 0) ? 1.0f : 0.0f;
  }
  __syncthreads();

  // matmul thread map: 16 tx (hh) x 16 ty (i)
  const int tx = tid & 15;
  const int ty = tid >> 4;
  const int c0 = tx * 4;        // hh cols c0..c0+3 and c0+64..c0+67
  const int c1 = c0 + 64;       // (split columns -> 2-way LDS banks, free)
  const int il = ty * 2;        // local i pair

  // staging thread map: 32 rows x 8 j-quads
  const int si = tid >> 3;            // local i row 0..31
  const int sj0 = (tid & 7) << 2;     // j offset within chunk
  const int gi = ibase + si;
  const float mi_s = maskf[gi];

  float acc[2][8];
#pragma unroll
  for (int r = 0; r < 2; ++r)
#pragma unroll
    for (int c = 0; c < 8; ++c) acc[r][c] = 0.0f;

  const float* dB = dist + (size_t)b * NV * NV;
  const float* bB = brg + (size_t)b * NV * NV;
  const float* gB = hdg + (size_t)b * NV * NV;

  for (int cs = 0; cs < NCHUNK; ++cs) {
    const int jc = cs * CH;

    // ---- stage weights w[i][j], i in block's 32 rows, j in chunk ----
    {
      const int g = gi * NV + jc + sj0;
      const float4 dd = *(const float4*)&dB[g];
      const float4 bb = *(const float4*)&bB[g];
      const float4 gg = *(const float4*)&gB[g];
      const float dv[4] = {dd.x, dd.y, dd.z, dd.w};
      const float bv[4] = {bb.x, bb.y, bb.z, bb.w};
      const float gv[4] = {gg.x, gg.y, gg.z, gg.w};
#pragma unroll
      for (int q = 0; q < 4; ++q) {
        const int jl = sj0 + q;
        float w = 0.0f;
        if (mi_s != 0.0f && maskf[jc + jl] != 0.0f) {
          // XLA rewrites /15.0 into * (1/15.0f) -- must bit-match buckets.
          const int i1 = min(23, max(0, (int)floorf(gv[q] * (1.0f / 15.0f))));
          const int i2 = min(23, max(0, (int)floorf(bv[q] * (1.0f / 15.0f))));
          const float t = dom[i1 * 24 + i2] - dv[q];
          w = fmaxf(t, 0.0f) + log1pf(expf(-fabsf(t)));  // stable softplus
        }
        wlds[jl * IB + si] = w;  // transposed write
      }
    }

    // ---- stage hidden rows j in chunk, linear [j][hh] ----
    {
      const int f4 = (tid & 31) << 2;
      const int jb = tid >> 5;
#pragma unroll
      for (int it = 0; it < 4; ++it) {
        const int jl = jb + it * 8;
        const float4 hv =
            *(const float4*)&hidden[((size_t)(jc + jl) * NBATCH + b) * NH + f4];
        *(float4*)&hlds[jl * NH + f4] = hv;
      }
    }
    __syncthreads();

    // ---- matmul: acc[r][c] += w[il+r][j] * h[j][col] ----
#pragma unroll
    for (int jj = 0; jj < CH; ++jj) {
      const float2 wv = *(const float2*)&wlds[jj * IB + il];
      const float4 h0 = *(const float4*)&hlds[jj * NH + c0];
      const float4 h1 = *(const float4*)&hlds[jj * NH + c1];
      const float hc[8] = {h0.x, h0.y, h0.z, h0.w, h1.x, h1.y, h1.z, h1.w};
      const float wr[2] = {wv.x, wv.y};
#pragma unroll
      for (int r = 0; r < 2; ++r)
#pragma unroll
        for (int c = 0; c < 8; ++c)
          acc[r][c] = fmaf(wr[r], hc[c], acc[r][c]);
    }
    __syncthreads();
  }

  // ---- epilogue: tanh + row mask + store (cols c0..c0+3, c1..c1+3) ----
  float* oB = out + (size_t)b * NV * NH;
#pragma unroll
  for (int r = 0; r < 2; ++r) {
    const int ig = ibase + il + r;
    const float m = maskf[ig];
    float4 o0, o1;
    o0.x = tanhf(acc[r][0]) * m;
    o0.y = tanhf(acc[r][1]) * m;
    o0.z = tanhf(acc[r][2]) * m;
    o0.w = tanhf(acc[r][3]) * m;
    o1.x = tanhf(acc[r][4]) * m;
    o1.y = tanhf(acc[r][5]) * m;
    o1.z = tanhf(acc[r][6]) * m;
    o1.w = tanhf(acc[r][7]) * m;
    *(float4*)&oB[ig * NH + c0] = o0;
    *(float4*)&oB[ig * NH + c1] = o1;
  }
}

extern "C" void kernel_launch(void* const* d_in, const int* in_sizes, int n_in,
                              void* d_out, int out_size, void* d_ws, size_t ws_size,
                              hipStream_t stream) {
  const float* hidden = (const float*)d_in[0];
  const float* dist = (const float*)d_in[1];
  const float* brg = (const float*)d_in[2];
  const float* hdg = (const float*)d_in[3];
  const unsigned char* mask = (const unsigned char*)d_in[4];
  const float* domain = (const float*)d_in[5];
  float* out = (float*)d_out;
  int* flag = (int*)d_ws;

  mask_detect_kernel<<<1, 256, 0, stream>>>(mask, flag);
  spatial_attn_kernel<<<NBATCH * 4, 256, 0, stream>>>(hidden, dist, brg, hdg,
                                                      mask, domain, flag, out);
}

// Round 6
// 42.190 us; speedup vs baseline: 1.5616x; 1.0912x over previous
//
#include <hip/hip_runtime.h>

#define NV 128     // vessels (N)
#define NB 256     // batches
#define NH 128     // hidden
#define KC 32      // K-chunk (j)
#define WSTR 40    // padded LDS row stride in shorts (16B-aligned, bank-spread)

typedef __attribute__((ext_vector_type(8))) unsigned short ushort8;
typedef __attribute__((ext_vector_type(4))) float f32x4;
typedef __attribute__((ext_vector_type(8))) __bf16 bf16x8;

__device__ __forceinline__ unsigned short f2bf(float x) {  // RNE f32->bf16
  unsigned u = __builtin_bit_cast(unsigned, x);
  return (unsigned short)((u + 0x7fffu + ((u >> 16) & 1u)) >> 16);
}
__device__ __forceinline__ float bf2f(unsigned short h) {
  return __builtin_bit_cast(float, (unsigned)h << 16);
}

// Detect byte-backed (numpy bool) vs word-backed mask: word-backed has
// byte1 == 0 everywhere.
__global__ void mask_detect_kernel(const unsigned char* __restrict__ mb,
                                   int* __restrict__ flag) {
  __shared__ int s;
  if (threadIdx.x == 0) s = 0;
  __syncthreads();
  int acc = 0;
  for (int i = threadIdx.x; i < 1024; i += blockDim.x) acc += mb[4 * i + 1];
  atomicAdd(&s, acc);
  __syncthreads();
  if (threadIdx.x == 0) *flag = (s == 0) ? 1 : 0;
}

__launch_bounds__(512)
__global__ void spatial_attn_mfma(const float* __restrict__ hidden,   // (N,B,H)
                                  const float* __restrict__ dist,     // (B,N,N)
                                  const float* __restrict__ brg,      // (B,N,N)
                                  const float* __restrict__ hdg,      // (B,N,N)
                                  const unsigned char* __restrict__ maskraw,
                                  const float* __restrict__ domain,   // (24,24)
                                  const int* __restrict__ flagp,
                                  float* __restrict__ out) {          // (B,N,H)
  // W (A-operand): [i][j-chunk] row-major, hi/lo bf16.  H^T (B-operand as
  // B^T rows): [hh][j-chunk], hi/lo bf16, column XOR-swizzled by (hh>>2)&3.
  __shared__ unsigned short whi[NV * WSTR], wlo[NV * WSTR];
  __shared__ unsigned short thi[NH * WSTR], tlo[NH * WSTR];
  __shared__ float dom[24 * 24];
  __shared__ float maskf[NV];

  const int tid = threadIdx.x;
  const int lane = tid & 63;
  const int wv = tid >> 6;          // wave 0..7 -> i-rows 16*wv..16*wv+15
  const int b = blockIdx.x;

  for (int k = tid; k < 576; k += 512) dom[k] = domain[k];
  if (tid < NV) {
    const int kind = *flagp;
    const int m = kind ? ((const int*)maskraw)[b * NV + tid]
                       : (int)maskraw[b * NV + tid];
    maskf[tid] = (m != 0) ? 1.0f : 0.0f;
  }
  __syncthreads();

  const int fm = lane & 15;         // fragment row/col within tile
  const int j0 = (lane >> 4) * 8;   // fragment k-slice (8 contiguous)
  const int arow = 16 * wv + fm;    // A row (global i) for this lane

  f32x4 acc[8];
#pragma unroll
  for (int t = 0; t < 8; ++t) acc[t] = (f32x4)0.0f;

  const float* dB = dist + (size_t)b * NV * NV;
  const float* bB = brg + (size_t)b * NV * NV;
  const float* gB = hdg + (size_t)b * NV * NV;

  for (int cs = 0; cs < 4; ++cs) {
    const int jc = cs * KC;

    // ---- stage W chunk: 128 i x 32 j, softplus weights -> bf16 hi/lo ----
#pragma unroll
    for (int y = 0; y < 2; ++y) {
      const int i = (tid >> 3) + 64 * y;
      const int jl0 = (tid & 7) << 2;
      const int g = i * NV + jc + jl0;
      const float4 dd = *(const float4*)&dB[g];
      const float4 bb = *(const float4*)&bB[g];
      const float4 gg = *(const float4*)&gB[g];
      const float mi = maskf[i];
      const float dv[4] = {dd.x, dd.y, dd.z, dd.w};
      const float bv[4] = {bb.x, bb.y, bb.z, bb.w};
      const float gv[4] = {gg.x, gg.y, gg.z, gg.w};
#pragma unroll
      for (int q = 0; q < 4; ++q) {
        const int jl = jl0 + q;
        float wt = 0.0f;
        if (mi != 0.0f && maskf[jc + jl] != 0.0f) {
          // XLA rewrites /15.0 to * (1/15.0f): must bit-match bucket edges.
          const int i1 = min(23, max(0, (int)floorf(gv[q] * (1.0f / 15.0f))));
          const int i2 = min(23, max(0, (int)floorf(bv[q] * (1.0f / 15.0f))));
          const float t = dom[i1 * 24 + i2] - dv[q];
          wt = fmaxf(t, 0.0f) + log1pf(expf(-fabsf(t)));  // stable softplus
        }
        const unsigned short hi = f2bf(wt);
        const unsigned short lo = f2bf(wt - bf2f(hi));
        whi[i * WSTR + jl] = hi;
        wlo[i * WSTR + jl] = lo;
      }
    }

    // ---- stage H^T chunk: 32 j x 128 hh -> [hh][j] bf16 hi/lo, swizzled ----
#pragma unroll
    for (int y = 0; y < 2; ++y) {
      const int fidx = tid + 512 * y;
      const int jl = fidx >> 5;
      const int hh0 = (fidx & 31) << 2;
      const float4 hv =
          *(const float4*)&hidden[((size_t)(jc + jl) * NB + b) * NH + hh0];
      const float hvv[4] = {hv.x, hv.y, hv.z, hv.w};
#pragma unroll
      for (int q = 0; q < 4; ++q) {
        const int hh = hh0 + q;
        const int col = jl ^ (((hh >> 2) & 3) << 3);
        const unsigned short hi = f2bf(hvv[q]);
        const unsigned short lo = f2bf(hvv[q] - bf2f(hi));
        thi[hh * WSTR + col] = hi;
        tlo[hh * WSTR + col] = lo;
      }
    }
    __syncthreads();

    // ---- MFMA: acc[t] += W[16wv..][jc..] * H[jc..][16t..] (bf16 x3) ----
    const bf16x8 ahi =
        __builtin_bit_cast(bf16x8, *(const ushort8*)&whi[arow * WSTR + j0]);
    const bf16x8 alo =
        __builtin_bit_cast(bf16x8, *(const ushort8*)&wlo[arow * WSTR + j0]);
#pragma unroll
    for (int t = 0; t < 8; ++t) {
      const int brow = 16 * t + fm;
      const int bcol = j0 ^ (((brow >> 2) & 3) << 3);
      const bf16x8 bhi =
          __builtin_bit_cast(bf16x8, *(const ushort8*)&thi[brow * WSTR + bcol]);
      const bf16x8 blo =
          __builtin_bit_cast(bf16x8, *(const ushort8*)&tlo[brow * WSTR + bcol]);
      acc[t] = __builtin_amdgcn_mfma_f32_16x16x32_bf16(ahi, bhi, acc[t], 0, 0, 0);
      acc[t] = __builtin_amdgcn_mfma_f32_16x16x32_bf16(ahi, blo, acc[t], 0, 0, 0);
      acc[t] = __builtin_amdgcn_mfma_f32_16x16x32_bf16(alo, bhi, acc[t], 0, 0, 0);
    }
    __syncthreads();
  }

  // ---- epilogue: tanh + row mask + store ----
  // C/D: col = lane&15, row = (lane>>4)*4 + reg   [m89-verified]
  float* oB = out + (size_t)b * NV * NH;
  const int rbase = 16 * wv + 4 * (lane >> 4);
#pragma unroll
  for (int t = 0; t < 8; ++t) {
    const int hh = 16 * t + fm;
#pragma unroll
    for (int r = 0; r < 4; ++r) {
      const int i = rbase + r;
      oB[i * NH + hh] = tanhf(acc[t][r]) * maskf[i];
    }
  }
}

extern "C" void kernel_launch(void* const* d_in, const int* in_sizes, int n_in,
                              void* d_out, int out_size, void* d_ws, size_t ws_size,
                              hipStream_t stream) {
  const float* hidden = (const float*)d_in[0];
  const float* dist = (const float*)d_in[1];
  const float* brg = (const float*)d_in[2];
  const float* hdg = (const float*)d_in[3];
  const unsigned char* mask = (const unsigned char*)d_in[4];
  const float* domain = (const float*)d_in[5];
  float* out = (float*)d_out;
  int* flag = (int*)d_ws;

  mask_detect_kernel<<<1, 256, 0, stream>>>(mask, flag);
  spatial_attn_mfma<<<NB, 512, 0, stream>>>(hidden, dist, brg, hdg, mask,
                                            domain, flag, out);
}

// Round 7
// 31.575 us; speedup vs baseline: 2.0866x; 1.3362x over previous
//
#include <hip/hip_runtime.h>

#define NV 128     // vessels (N)
#define NB 256     // batches
#define NH 128     // hidden
#define KC 32      // K-chunk (j)
#define IB 64      // i-rows per block
#define HSTR 40    // H LDS row stride in shorts (80 B: 16B-aligned, 20%32 bank-partitions)

typedef __attribute__((ext_vector_type(8))) unsigned short ushort8;
typedef __attribute__((ext_vector_type(4))) float f32x4;
typedef __attribute__((ext_vector_type(8))) __bf16 bf16x8;

__device__ __forceinline__ unsigned short f2bf(float x) {  // RNE f32->bf16
  unsigned u = __builtin_bit_cast(unsigned, x);
  return (unsigned short)((u + 0x7fffu + ((u >> 16) & 1u)) >> 16);
}
__device__ __forceinline__ float bf2f(unsigned short h) {
  return __builtin_bit_cast(float, (unsigned)h << 16);
}

// Detect byte-backed (numpy bool) vs word-backed mask: word-backed has
// byte1 == 0 everywhere.
__global__ void mask_detect_kernel(const unsigned char* __restrict__ mb,
                                   int* __restrict__ flag) {
  __shared__ int s;
  if (threadIdx.x == 0) s = 0;
  __syncthreads();
  int acc = 0;
  for (int i = threadIdx.x; i < 1024; i += blockDim.x) acc += mb[4 * i + 1];
  atomicAdd(&s, acc);
  __syncthreads();
  if (threadIdx.x == 0) *flag = (s == 0) ? 1 : 0;
}

__launch_bounds__(256)
__global__ void spatial_attn_mfma(const float* __restrict__ hidden,   // (N,B,H)
                                  const float* __restrict__ dist,     // (B,N,N)
                                  const float* __restrict__ brg,      // (B,N,N)
                                  const float* __restrict__ hdg,      // (B,N,N)
                                  const unsigned char* __restrict__ maskraw,
                                  const float* __restrict__ domain,   // (24,24)
                                  const int* __restrict__ flagp,
                                  float* __restrict__ out) {          // (B,N,H)
  // H^T (B-operand rows): [hh][j-chunk] bf16 hi/lo, double-buffered.
  __shared__ unsigned short thi[2][NH * HSTR];
  __shared__ unsigned short tlo[2][NH * HSTR];
  __shared__ float dom[24 * 24];
  __shared__ float maskf[NV];

  const int tid = threadIdx.x;
  const int lane = tid & 63;
  const int wv = tid >> 6;                 // wave 0..3
  const int b = blockIdx.x >> 1;           // batch
  const int ibase = (blockIdx.x & 1) * IB; // i-half

  for (int k = tid; k < 576; k += 256) dom[k] = domain[k];
  if (tid < NV) {
    const int kind = *flagp;
    const int m = kind ? ((const int*)maskraw)[b * NV + tid]
                       : (int)maskraw[b * NV + tid];
    maskf[tid] = (m != 0) ? 1.0f : 0.0f;
  }
  __syncthreads();

  // MFMA fragment geometry (m89-verified, same as passing R6 kernel)
  const int fm = lane & 15;
  const int j0 = (lane >> 4) * 8;
  const int arow = ibase + 16 * wv + fm;   // this lane's A row (global i)
  const float mi = maskf[arow];

  // H staging map: thread -> one hh row, 16 j's
  const int shh = tid & 127;
  const int sjh = (tid >> 7) * 16;

  f32x4 acc[8];
#pragma unroll
  for (int t = 0; t < 8; ++t) acc[t] = (f32x4)0.0f;

  const float* dR = dist + ((size_t)b * NV + arow) * NV;
  const float* bR = brg + ((size_t)b * NV + arow) * NV;
  const float* gR = hdg + ((size_t)b * NV + arow) * NV;

  // ---- stage H chunk into buffer bb: per-thread one hh row, j contiguous ----
#define STAGE_H(cc, bb)                                                       \
  {                                                                           \
    const int jb = (cc) * KC + sjh;                                           \
    float v[16];                                                              \
    _Pragma("unroll") for (int k = 0; k < 16; ++k)                            \
        v[k] = hidden[((size_t)(jb + k) * NB + b) * NH + shh];                \
    ushort8 ph0, ph1, pl0, pl1;                                               \
    _Pragma("unroll") for (int k = 0; k < 8; ++k) {                           \
      unsigned short h = f2bf(v[k]);                                          \
      ph0[k] = h;                                                             \
      pl0[k] = f2bf(v[k] - bf2f(h));                                          \
    }                                                                         \
    _Pragma("unroll") for (int k = 0; k < 8; ++k) {                           \
      unsigned short h = f2bf(v[8 + k]);                                      \
      ph1[k] = h;                                                             \
      pl1[k] = f2bf(v[8 + k] - bf2f(h));                                      \
    }                                                                         \
    *(ushort8*)&thi[bb][shh * HSTR + sjh] = ph0;                              \
    *(ushort8*)&thi[bb][shh * HSTR + sjh + 8] = ph1;                          \
    *(ushort8*)&tlo[bb][shh * HSTR + sjh] = pl0;                              \
    *(ushort8*)&tlo[bb][shh * HSTR + sjh + 8] = pl1;                          \
  }

  STAGE_H(0, 0);

  for (int cs = 0; cs < 4; ++cs) {
    const int jc = cs * KC;
    const int cb = cs & 1;

    // ---- W: this lane's A-fragment, computed in registers (no LDS) ----
    const float4 d0 = *(const float4*)&dR[jc + j0];
    const float4 d1 = *(const float4*)&dR[jc + j0 + 4];
    const float4 b0 = *(const float4*)&bR[jc + j0];
    const float4 b1 = *(const float4*)&bR[jc + j0 + 4];
    const float4 g0 = *(const float4*)&gR[jc + j0];
    const float4 g1 = *(const float4*)&gR[jc + j0 + 4];

    __syncthreads();                       // H(cs) staged; prev MFMA done
    if (cs < 3) STAGE_H(cs + 1, cb ^ 1);   // prefetch next chunk

    const float dv[8] = {d0.x, d0.y, d0.z, d0.w, d1.x, d1.y, d1.z, d1.w};
    const float bv[8] = {b0.x, b0.y, b0.z, b0.w, b1.x, b1.y, b1.z, b1.w};
    const float gv[8] = {g0.x, g0.y, g0.z, g0.w, g1.x, g1.y, g1.z, g1.w};
    ushort8 ahi_u, alo_u;
#pragma unroll
    for (int e = 0; e < 8; ++e) {
      float w = 0.0f;
      if (mi != 0.0f && maskf[jc + j0 + e] != 0.0f) {
        // XLA rewrites /15.0 to * (1/15.0f): must bit-match bucket edges.
        const int i1 = min(23, max(0, (int)floorf(gv[e] * (1.0f / 15.0f))));
        const int i2 = min(23, max(0, (int)floorf(bv[e] * (1.0f / 15.0f))));
        const float t = dom[i1 * 24 + i2] - dv[e];
        // fast stable softplus: max(t,0) + log(1 + exp(-|t|))
        w = fmaxf(t, 0.0f) + __logf(1.0f + __expf(-fabsf(t)));
      }
      const unsigned short h = f2bf(w);
      ahi_u[e] = h;
      alo_u[e] = f2bf(w - bf2f(h));
    }
    const bf16x8 ahi = __builtin_bit_cast(bf16x8, ahi_u);
    const bf16x8 alo = __builtin_bit_cast(bf16x8, alo_u);

    // ---- MFMA: acc[t] += W * H (bf16 hi/lo x3) ----
#pragma unroll
    for (int t = 0; t < 8; ++t) {
      const int boff = (16 * t + fm) * HSTR + j0;
      const bf16x8 bhi = __builtin_bit_cast(bf16x8, *(const ushort8*)&thi[cb][boff]);
      const bf16x8 blo = __builtin_bit_cast(bf16x8, *(const ushort8*)&tlo[cb][boff]);
      acc[t] = __builtin_amdgcn_mfma_f32_16x16x32_bf16(ahi, bhi, acc[t], 0, 0, 0);
      acc[t] = __builtin_amdgcn_mfma_f32_16x16x32_bf16(ahi, blo, acc[t], 0, 0, 0);
      acc[t] = __builtin_amdgcn_mfma_f32_16x16x32_bf16(alo, bhi, acc[t], 0, 0, 0);
    }
  }

  // ---- epilogue: fast tanh + row mask + store ----
  // C/D: col = lane&15, row = (lane>>4)*4 + reg
  float* oB = out + (size_t)b * NV * NH;
  const int rbase = ibase + 16 * wv + 4 * (lane >> 4);
#pragma unroll
  for (int t = 0; t < 8; ++t) {
    const int hh = 16 * t + fm;
#pragma unroll
    for (int r = 0; r < 4; ++r) {
      const int i = rbase + r;
      const float x = acc[t][r];
      const float ex = __expf(2.0f * x);             // inf-safe: ->1 / ->-1
      const float th = 1.0f - __fdividef(2.0f, ex + 1.0f);
      oB[i * NH + hh] = th * maskf[i];
    }
  }
}

extern "C" void kernel_launch(void* const* d_in, const int* in_sizes, int n_in,
                              void* d_out, int out_size, void* d_ws, size_t ws_size,
                              hipStream_t stream) {
  const float* hidden = (const float*)d_in[0];
  const float* dist = (const float*)d_in[1];
  const float* brg = (const float*)d_in[2];
  const float* hdg = (const float*)d_in[3];
  const unsigned char* mask = (const unsigned char*)d_in[4];
  const float* domain = (const float*)d_in[5];
  float* out = (float*)d_out;
  int* flag = (int*)d_ws;

  mask_detect_kernel<<<1, 256, 0, stream>>>(mask, flag);
  spatial_attn_mfma<<<NB * 2, 256, 0, stream>>>(hidden, dist, brg, hdg, mask,
                                                domain, flag, out);
}